// Round 1
// baseline (624.052 us; speedup 1.0000x reference)
//
#include <hip/hip_runtime.h>
#include <math.h>
#include <float.h>

#define BN_EPS 1e-5f

// ---------------------------------------------------------------------------
// Kernel 1: edge scatter  agg[dst] += x[src]   (wave per edge, lane = feature)
// ---------------------------------------------------------------------------
__global__ __launch_bounds__(256) void edge_scatter(
    const int* __restrict__ src, const int* __restrict__ dst,
    const float* __restrict__ x, float* agg, int E)
{
    int e = blockIdx.x * 4 + (threadIdx.x >> 6);
    int lane = threadIdx.x & 63;
    if (e < E) {
        int s = src[e];
        int d = dst[e];
        atomicAdd(&agg[(size_t)d * 64 + lane], x[(size_t)s * 64 + lane]);
    }
}

// ---------------------------------------------------------------------------
// Kernel 2: node MLP.  h = relu(relu((x+agg)@W1+b1)@W2+b2); gate = h@Wg+bg
// wave-per-node; W1/W2 in LDS; input row broadcast via __shfl.
// h_out may alias agg_in (row read before row write, same wave).
// ---------------------------------------------------------------------------
__global__ __launch_bounds__(256) void node_mlp(
    const float* __restrict__ x, const float* agg_in,
    const float* __restrict__ W1, const float* __restrict__ b1,
    const float* __restrict__ W2, const float* __restrict__ b2,
    const float* __restrict__ Wg, const float* __restrict__ bg,
    float* h_out, float* __restrict__ gate_out, int N)
{
    __shared__ float W1s[64 * 64];
    __shared__ float W2s[64 * 64];
    __shared__ float b1s[64], b2s[64], Wgs[64];

    int tid = threadIdx.x;
    for (int i = tid; i < 64 * 64; i += 256) {
        W1s[i] = W1[i];
        W2s[i] = W2[i];
    }
    if (tid < 64) {
        b1s[tid] = b1[tid];
        b2s[tid] = b2[tid];
        Wgs[tid] = Wg[tid];
    }
    __syncthreads();

    float bgv = bg[0];
    int lane = tid & 63;
    int wave = tid >> 6;
    int stride = gridDim.x * 4;

    for (int node = blockIdx.x * 4 + wave; node < N; node += stride) {
        size_t row = (size_t)node * 64;
        float v = x[row + lane] + agg_in[row + lane];

        float acc = b1s[lane];
        #pragma unroll
        for (int k = 0; k < 64; ++k)
            acc = fmaf(__shfl(v, k), W1s[k * 64 + lane], acc);
        float h1 = fmaxf(acc, 0.f);

        float acc2 = b2s[lane];
        #pragma unroll
        for (int k = 0; k < 64; ++k)
            acc2 = fmaf(__shfl(h1, k), W2s[k * 64 + lane], acc2);
        float h2 = fmaxf(acc2, 0.f);

        h_out[row + lane] = h2;

        float gp = h2 * Wgs[lane];
        #pragma unroll
        for (int off = 32; off; off >>= 1)
            gp += __shfl_xor(gp, off);
        if (lane == 0)
            gate_out[node] = gp + bgv;
    }
}

// ---------------------------------------------------------------------------
// Kernel 3: per-graph softmax-attention pooling + BN(eval) + linear + lsm.
// batch is sorted -> binary search the contiguous node range of graph g.
// One 256-thread block per graph. No atomics.
// ---------------------------------------------------------------------------
__global__ __launch_bounds__(256) void pool_final(
    const float* __restrict__ h, const float* __restrict__ gate,
    const int* __restrict__ batch,
    const float* __restrict__ gamma_, const float* __restrict__ beta_,
    const float* __restrict__ mean_, const float* __restrict__ var_,
    const float* __restrict__ Wl, const float* __restrict__ bl,
    float* __restrict__ out, int N)
{
    int g = blockIdx.x;
    int tid = threadIdx.x;

    // lower_bound(batch, g) and lower_bound(batch, g+1)
    int lo = 0, hi = N;
    while (lo < hi) { int mid = (lo + hi) >> 1; if (batch[mid] < g) lo = mid + 1; else hi = mid; }
    int start = lo;
    hi = N;
    while (lo < hi) { int mid = (lo + hi) >> 1; if (batch[mid] < g + 1) lo = mid + 1; else hi = mid; }
    int end = lo;

    __shared__ float red[4];
    __shared__ float pool_s[4 * 64];

    int lane = tid & 63;
    int wave = tid >> 6;

    // phase 1: segment max of gate
    float m = -FLT_MAX;
    for (int i = start + tid; i < end; i += 256) m = fmaxf(m, gate[i]);
    #pragma unroll
    for (int off = 32; off; off >>= 1) m = fmaxf(m, __shfl_xor(m, off));
    if (lane == 0) red[wave] = m;
    __syncthreads();
    m = fmaxf(fmaxf(red[0], red[1]), fmaxf(red[2], red[3]));
    __syncthreads();

    // phase 2: segment sum of exp(gate - m)
    float s = 0.f;
    for (int i = start + tid; i < end; i += 256) s += expf(gate[i] - m);
    #pragma unroll
    for (int off = 32; off; off >>= 1) s += __shfl_xor(s, off);
    if (lane == 0) red[wave] = s;
    __syncthreads();
    s = red[0] + red[1] + red[2] + red[3];

    // phase 3: weighted feature sum (wave strides nodes, lane = feature)
    float acc = 0.f;
    for (int i = start + wave; i < end; i += 4) {
        float e = expf(gate[i] - m);
        acc = fmaf(e, h[(size_t)i * 64 + lane], acc);
    }
    pool_s[wave * 64 + lane] = acc;
    __syncthreads();

    // phase 4: BN + linear(64x2) + log_softmax, wave 0 only
    if (wave == 0) {
        float p = pool_s[lane] + pool_s[64 + lane] + pool_s[128 + lane] + pool_s[192 + lane];
        p = (end > start) ? (p / s) : 0.f;
        float nrm = (p - mean_[lane]) / sqrtf(var_[lane] + BN_EPS) * gamma_[lane] + beta_[lane];
        float l0 = nrm * Wl[lane * 2 + 0];
        float l1 = nrm * Wl[lane * 2 + 1];
        #pragma unroll
        for (int off = 32; off; off >>= 1) {
            l0 += __shfl_xor(l0, off);
            l1 += __shfl_xor(l1, off);
        }
        if (lane == 0) {
            l0 += bl[0];
            l1 += bl[1];
            float mx = fmaxf(l0, l1);
            float lse = mx + logf(expf(l0 - mx) + expf(l1 - mx));
            out[g * 2 + 0] = l0 - lse;
            out[g * 2 + 1] = l1 - lse;
        }
    }
}

// ---------------------------------------------------------------------------
extern "C" void kernel_launch(void* const* d_in, const int* in_sizes, int n_in,
                              void* d_out, int out_size, void* d_ws, size_t ws_size,
                              hipStream_t stream)
{
    const float* x     = (const float*)d_in[0];
    const int*   eidx  = (const int*)d_in[1];   // [2, E] flat: row0=src, row1=dst
    const int*   batch = (const int*)d_in[2];
    const float* W1    = (const float*)d_in[3];
    const float* b1    = (const float*)d_in[4];
    const float* W2    = (const float*)d_in[5];
    const float* b2    = (const float*)d_in[6];
    const float* Wg    = (const float*)d_in[7];
    const float* bg    = (const float*)d_in[8];
    const float* bng   = (const float*)d_in[9];
    const float* bnb   = (const float*)d_in[10];
    const float* bnm   = (const float*)d_in[11];
    const float* bnv   = (const float*)d_in[12];
    const float* Wl    = (const float*)d_in[13];
    const float* bl    = (const float*)d_in[14];
    float* out = (float*)d_out;

    int N = in_sizes[0] / 64;
    int E = in_sizes[1] / 2;
    int G = out_size / 2;

    float* agg  = (float*)d_ws;          // N*64 floats; reused as h
    float* gate = agg + (size_t)N * 64;  // N floats

    hipMemsetAsync(agg, 0, (size_t)N * 64 * sizeof(float), stream);

    edge_scatter<<<(E + 3) / 4, 256, 0, stream>>>(eidx, eidx + E, x, agg, E);

    node_mlp<<<1024, 256, 0, stream>>>(x, agg, W1, b1, W2, b2, Wg, bg,
                                       agg /* h aliases agg */, gate, N);

    pool_final<<<G, 256, 0, stream>>>(agg, gate, batch, bng, bnb, bnm, bnv,
                                      Wl, bl, out, N);
}

// Round 2
// 583.305 us; speedup vs baseline: 1.0699x; 1.0699x over previous
//
#include <hip/hip_runtime.h>
#include <math.h>
#include <float.h>

#define BN_EPS 1e-5f

__device__ __forceinline__ float readlane_f(float v, int l) {
    return __int_as_float(__builtin_amdgcn_readlane(__float_as_int(v), l));
}

// ---------------------------------------------------------------------------
// Kernel 1: in-degree histogram
// ---------------------------------------------------------------------------
__global__ __launch_bounds__(256) void deg_hist(
    const int* __restrict__ dst, int* deg, int E)
{
    int e = blockIdx.x * 256 + threadIdx.x;
    if (e < E) atomicAdd(&deg[dst[e]], 1);
}

// ---------------------------------------------------------------------------
// Kernel 2a: per-block exclusive scan of deg (256/block), write block sums
// ---------------------------------------------------------------------------
__global__ __launch_bounds__(256) void scan_block(
    const int* __restrict__ deg, int* __restrict__ excl,
    int* __restrict__ bsum, int N)
{
    int tid = threadIdx.x;
    int i = blockIdx.x * 256 + tid;
    int lane = tid & 63, wave = tid >> 6;
    int orig = (i < N) ? deg[i] : 0;
    int v = orig;
    #pragma unroll
    for (int d = 1; d < 64; d <<= 1) {
        int t = __shfl_up(v, d);
        if (lane >= d) v += t;
    }
    __shared__ int ws[4];
    if (lane == 63) ws[wave] = v;
    __syncthreads();
    int woff = 0;
    for (int w = 0; w < wave; ++w) woff += ws[w];
    int incl = v + woff;
    if (i < N) excl[i] = incl - orig;
    if (tid == 255) bsum[blockIdx.x] = incl;
}

// ---------------------------------------------------------------------------
// Kernel 2b: scan the block sums (NB <= 512), in place -> exclusive offsets
// ---------------------------------------------------------------------------
__global__ __launch_bounds__(512) void scan_tops(int* bsum, int NB)
{
    __shared__ int s[512];
    int tid = threadIdx.x;
    int v = (tid < NB) ? bsum[tid] : 0;
    s[tid] = v;
    __syncthreads();
    for (int d = 1; d < 512; d <<= 1) {
        int t = (tid >= d) ? s[tid - d] : 0;
        __syncthreads();
        s[tid] += t;
        __syncthreads();
    }
    if (tid < NB) bsum[tid] = s[tid] - v;   // exclusive
}

// ---------------------------------------------------------------------------
// Kernel 2c: combine -> row_start[i], cursor[i]; row_start[N] = E
// ---------------------------------------------------------------------------
__global__ __launch_bounds__(256) void scan_add(
    const int* __restrict__ excl, const int* __restrict__ bsum,
    int* __restrict__ row_start, int* __restrict__ cursor, int N, int E)
{
    int i = blockIdx.x * 256 + threadIdx.x;
    if (i < N) {
        int r = excl[i] + bsum[i >> 8];
        row_start[i] = r;
        cursor[i] = r;
    }
    if (i == 0) row_start[N] = E;
}

// ---------------------------------------------------------------------------
// Kernel 3: place edge src ids into CSR slots
// ---------------------------------------------------------------------------
__global__ __launch_bounds__(256) void edge_place(
    const int* __restrict__ src, const int* __restrict__ dst,
    int* cursor, int* __restrict__ eord, int E)
{
    int e = blockIdx.x * 256 + threadIdx.x;
    if (e < E) {
        int pos = atomicAdd(&cursor[dst[e]], 1);
        eord[pos] = src[e];
    }
}

// ---------------------------------------------------------------------------
// Kernel 4: fused gather + MLP.  Wave per node:
//   v = x[d] + sum_{s in in(d)} x[s];  h = relu(relu(v@W1+b1)@W2+b2);
//   gate = h@Wg+bg.  Broadcasts via v_readlane (VALU, not LDS pipe).
// ---------------------------------------------------------------------------
__global__ __launch_bounds__(256) void fused_mlp(
    const float* __restrict__ x,
    const int* __restrict__ eord, const int* __restrict__ row_start,
    const float* __restrict__ W1, const float* __restrict__ b1,
    const float* __restrict__ W2, const float* __restrict__ b2,
    const float* __restrict__ Wg, const float* __restrict__ bg,
    float* __restrict__ h_out, float* __restrict__ gate_out, int N)
{
    __shared__ float W1s[64 * 64];
    __shared__ float W2s[64 * 64];
    __shared__ float b1s[64], b2s[64], Wgs[64];

    int tid = threadIdx.x;
    for (int i = tid; i < 64 * 64; i += 256) {
        W1s[i] = W1[i];
        W2s[i] = W2[i];
    }
    if (tid < 64) {
        b1s[tid] = b1[tid];
        b2s[tid] = b2[tid];
        Wgs[tid] = Wg[tid];
    }
    __syncthreads();

    float bgv = bg[0];
    int lane = tid & 63;
    int wave = tid >> 6;
    int stride = gridDim.x * 4;

    for (int node = blockIdx.x * 4 + wave; node < N; node += stride) {
        size_t row = (size_t)node * 64;
        int beg = row_start[node];
        int end = row_start[node + 1];

        float v = x[row + lane];
        for (int base = beg; base < end; base += 64) {
            int ei = (base + lane < end) ? eord[base + lane] : 0;
            int cnt = end - base; if (cnt > 64) cnt = 64;
            for (int j = 0; j < cnt; ++j) {
                int s = __builtin_amdgcn_readlane(ei, j);
                v += x[(size_t)s * 64 + lane];
            }
        }

        float acc = b1s[lane];
        #pragma unroll
        for (int k = 0; k < 64; ++k)
            acc = fmaf(readlane_f(v, k), W1s[k * 64 + lane], acc);
        float h1 = fmaxf(acc, 0.f);

        float acc2 = b2s[lane];
        #pragma unroll
        for (int k = 0; k < 64; ++k)
            acc2 = fmaf(readlane_f(h1, k), W2s[k * 64 + lane], acc2);
        float h2 = fmaxf(acc2, 0.f);

        h_out[row + lane] = h2;

        float gp = h2 * Wgs[lane];
        #pragma unroll
        for (int off = 32; off; off >>= 1)
            gp += __shfl_xor(gp, off);
        if (lane == 0)
            gate_out[node] = gp + bgv;
    }
}

// ---------------------------------------------------------------------------
// Kernel 5: per-graph softmax-attention pooling + BN(eval) + linear + lsm.
// batch is sorted -> binary search the contiguous node range of graph g.
// ---------------------------------------------------------------------------
__global__ __launch_bounds__(256) void pool_final(
    const float* __restrict__ h, const float* __restrict__ gate,
    const int* __restrict__ batch,
    const float* __restrict__ gamma_, const float* __restrict__ beta_,
    const float* __restrict__ mean_, const float* __restrict__ var_,
    const float* __restrict__ Wl, const float* __restrict__ bl,
    float* __restrict__ out, int N)
{
    int g = blockIdx.x;
    int tid = threadIdx.x;

    int lo = 0, hi = N;
    while (lo < hi) { int mid = (lo + hi) >> 1; if (batch[mid] < g) lo = mid + 1; else hi = mid; }
    int start = lo;
    hi = N;
    while (lo < hi) { int mid = (lo + hi) >> 1; if (batch[mid] < g + 1) lo = mid + 1; else hi = mid; }
    int end = lo;

    __shared__ float red[4];
    __shared__ float pool_s[4 * 64];

    int lane = tid & 63;
    int wave = tid >> 6;

    // segment max of gate
    float m = -FLT_MAX;
    for (int i = start + tid; i < end; i += 256) m = fmaxf(m, gate[i]);
    #pragma unroll
    for (int off = 32; off; off >>= 1) m = fmaxf(m, __shfl_xor(m, off));
    if (lane == 0) red[wave] = m;
    __syncthreads();
    m = fmaxf(fmaxf(red[0], red[1]), fmaxf(red[2], red[3]));
    __syncthreads();

    // segment sum of exp
    float s = 0.f;
    for (int i = start + tid; i < end; i += 256) s += expf(gate[i] - m);
    #pragma unroll
    for (int off = 32; off; off >>= 1) s += __shfl_xor(s, off);
    if (lane == 0) red[wave] = s;
    __syncthreads();
    s = red[0] + red[1] + red[2] + red[3];

    // weighted feature sum
    float acc = 0.f;
    for (int i = start + wave; i < end; i += 4) {
        float e = expf(gate[i] - m);
        acc = fmaf(e, h[(size_t)i * 64 + lane], acc);
    }
    pool_s[wave * 64 + lane] = acc;
    __syncthreads();

    // BN + linear(64x2) + log_softmax
    if (wave == 0) {
        float p = pool_s[lane] + pool_s[64 + lane] + pool_s[128 + lane] + pool_s[192 + lane];
        p = (end > start) ? (p / s) : 0.f;
        float nrm = (p - mean_[lane]) / sqrtf(var_[lane] + BN_EPS) * gamma_[lane] + beta_[lane];
        float l0 = nrm * Wl[lane * 2 + 0];
        float l1 = nrm * Wl[lane * 2 + 1];
        #pragma unroll
        for (int off = 32; off; off >>= 1) {
            l0 += __shfl_xor(l0, off);
            l1 += __shfl_xor(l1, off);
        }
        if (lane == 0) {
            l0 += bl[0];
            l1 += bl[1];
            float mx = fmaxf(l0, l1);
            float lse = mx + logf(expf(l0 - mx) + expf(l1 - mx));
            out[g * 2 + 0] = l0 - lse;
            out[g * 2 + 1] = l1 - lse;
        }
    }
}

// ---------------------------------------------------------------------------
extern "C" void kernel_launch(void* const* d_in, const int* in_sizes, int n_in,
                              void* d_out, int out_size, void* d_ws, size_t ws_size,
                              hipStream_t stream)
{
    const float* x     = (const float*)d_in[0];
    const int*   eidx  = (const int*)d_in[1];   // [2, E]: row0=src, row1=dst
    const int*   batch = (const int*)d_in[2];
    const float* W1    = (const float*)d_in[3];
    const float* b1    = (const float*)d_in[4];
    const float* W2    = (const float*)d_in[5];
    const float* b2    = (const float*)d_in[6];
    const float* Wg    = (const float*)d_in[7];
    const float* bg    = (const float*)d_in[8];
    const float* bng   = (const float*)d_in[9];
    const float* bnb   = (const float*)d_in[10];
    const float* bnm   = (const float*)d_in[11];
    const float* bnv   = (const float*)d_in[12];
    const float* Wl    = (const float*)d_in[13];
    const float* bl    = (const float*)d_in[14];
    float* out = (float*)d_out;

    int N = in_sizes[0] / 64;
    int E = in_sizes[1] / 2;
    int G = out_size / 2;
    int NB = (N + 255) / 256;   // scan blocks (<= 512 required)

    // workspace layout
    char* w = (char*)d_ws;
    float* h        = (float*)w;                 w += (size_t)N * 64 * sizeof(float);
    float* gate     = (float*)w;                 w += (size_t)N * sizeof(float);
    int*   deg      = (int*)w;                   w += (size_t)N * sizeof(int);
    int*   excl     = (int*)w;                   w += (size_t)N * sizeof(int);
    int*   row_start= (int*)w;                   w += (size_t)(N + 1) * sizeof(int);
    int*   cursor   = (int*)w;                   w += (size_t)N * sizeof(int);
    int*   bsum     = (int*)w;                   w += (size_t)512 * sizeof(int);
    int*   eord     = (int*)w;                   // E ints

    const int* src = eidx;
    const int* dst = eidx + E;

    hipMemsetAsync(deg, 0, (size_t)N * sizeof(int), stream);

    deg_hist  <<<(E + 255) / 256, 256, 0, stream>>>(dst, deg, E);
    scan_block<<<NB, 256, 0, stream>>>(deg, excl, bsum, N);
    scan_tops <<<1, 512, 0, stream>>>(bsum, NB);
    scan_add  <<<NB, 256, 0, stream>>>(excl, bsum, row_start, cursor, N, E);
    edge_place<<<(E + 255) / 256, 256, 0, stream>>>(src, dst, cursor, eord, E);

    fused_mlp <<<1280, 256, 0, stream>>>(x, eord, row_start, W1, b1, W2, b2,
                                         Wg, bg, h, gate, N);

    pool_final<<<G, 256, 0, stream>>>(h, gate, batch, bng, bnb, bnm, bnv,
                                      Wl, bl, out, N);
}